// Round 15
// baseline (212.056 us; speedup 1.0000x reference)
//
#include <hip/hip_runtime.h>

using half8 = __attribute__((ext_vector_type(8))) _Float16;
using f32x4 = __attribute__((ext_vector_type(4))) float;

__device__ __forceinline__ float sigmf(float x) {
    return __builtin_amdgcn_rcpf(1.0f + __expf(-x));
}
__device__ __forceinline__ float tanhx(float x) {
    return 1.0f - 2.0f * __builtin_amdgcn_rcpf(1.0f + __expf(x + x));
}
// load 8 consecutive f32 and convert to half8 (32B-aligned sources)
__device__ __forceinline__ half8 cvt8(const float* p) {
    f32x4 a = *(const f32x4*)p;
    f32x4 b = *(const f32x4*)(p + 4);
    half8 r;
    r[0] = (_Float16)a[0]; r[1] = (_Float16)a[1];
    r[2] = (_Float16)a[2]; r[3] = (_Float16)a[3];
    r[4] = (_Float16)b[0]; r[5] = (_Float16)b[1];
    r[6] = (_Float16)b[2]; r[7] = (_Float16)b[3];
    return r;
}

// ---------------------------------------------------------------------------
// Prep: ONLY lwI = lin_w as [75][4][16][32] fp16.
// ---------------------------------------------------------------------------
__global__ __launch_bounds__(256) void prep_lw(const float* __restrict__ lw,
                                               _Float16* __restrict__ lwI) {
    int i = blockIdx.x * 256 + threadIdx.x;
    if (i >= 153600) return;
    int t = i >> 11;
    int rem = i & 2047;
    int tile = rem >> 9, op = (rem >> 5) & 15, hc = rem & 31;
    int o = tile * 16 + op;
    float v = (o < 60) ? lw[(size_t)o * 2400 + t * 32 + hc] : 0.0f;
    lwI[i] = (_Float16)v;
}

// ---------------------------------------------------------------------------
// Layer-0 xg GEMM: reads f32 x AND f32 wih0 directly (converts during LDS
// staging; W rows interleaved on the fly: n -> src (n&3)*128+(n>>2)).
// Output layout [75][28][512][4] f32 (round-7 proven fragment layout).
// ---------------------------------------------------------------------------
__global__ __launch_bounds__(256) void gemm_xg0(
    const float* __restrict__ X,        // [100][75][75] f32
    const float* __restrict__ W0,       // wih0 [512][75] f32
    const float* __restrict__ bi0, const float* __restrict__ bh0,
    float* __restrict__ C) {
    constexpr int Ks = 3, LDK = 104, HP = 48, N = 512;
    __shared__ __align__(16) _Float16 Al[64][LDK];
    __shared__ __align__(16) _Float16 Wl[64][LDK];

    const int tid = threadIdx.x;
    const int tt = blockIdx.x >> 1;
    const int boff = (blockIdx.x & 1) * 48;
    const int n0 = blockIdx.y * 64;

    for (int idx = tid; idx < 64 * HP; idx += 256) {
        int row = idx / HP;
        int k = (idx - row * HP) * 2;
        unsigned int va = 0, vw = 0;
        int b = boff + row;
        if (b < 100 && k < 75) {
            float f0 = X[((size_t)b * 75 + tt) * 75 + k];
            float f1 = (k + 1 < 75) ? X[((size_t)b * 75 + tt) * 75 + k + 1] : 0.0f;
            _Float16 h2[2] = {(_Float16)f0, (_Float16)f1};
            va = *(unsigned int*)h2;
        }
        if (k < 75) {
            int n = n0 + row;
            int src = (n & 3) * 128 + (n >> 2);
            float f0 = W0[(size_t)src * 75 + k];
            float f1 = (k + 1 < 75) ? W0[(size_t)src * 75 + k + 1] : 0.0f;
            _Float16 h2[2] = {(_Float16)f0, (_Float16)f1};
            vw = *(unsigned int*)h2;
        }
        *(unsigned int*)&Al[row][k] = va;
        *(unsigned int*)&Wl[row][k] = vw;
    }
    __syncthreads();

    const int w = tid >> 6, l = tid & 63, hi = l >> 4;
    half8 a[Ks];
    #pragma unroll
    for (int kk = 0; kk < Ks; ++kk)
        a[kk] = *(const half8*)&Al[w * 16 + (l & 15)][kk * 32 + hi * 8];

    f32x4 acc[4];
    #pragma unroll
    for (int jt = 0; jt < 4; ++jt) {
        acc[jt] = f32x4{0.f, 0.f, 0.f, 0.f};
        #pragma unroll
        for (int kk = 0; kk < Ks; ++kk) {
            half8 b = *(const half8*)&Wl[jt * 16 + (l & 15)][kk * 32 + hi * 8];
            acc[jt] = __builtin_amdgcn_mfma_f32_16x16x32_f16(a[kk], b, acc[jt], 0, 0, 0);
        }
    }

    const int bx = (boff >> 2) + w * 4 + hi;
    #pragma unroll
    for (int jt = 0; jt < 4; ++jt) {
        int n = n0 + jt * 16 + (l & 15);
        int src = (n & 3) * 128 + (n >> 2);
        float bs = bi0[src] + bh0[src];
        f32x4 v = acc[jt];
        v[0] += bs; v[1] += bs; v[2] += bs; v[3] += bs;
        *(f32x4*)(C + ((size_t)(tt * 28 + bx) * N + n) * 4) = v;
    }
}

// ---------------------------------------------------------------------------
// Layer-1 xg GEMM: A = h0 fp16, W = f32 wih1 (interleaved on load).
// ---------------------------------------------------------------------------
__global__ __launch_bounds__(256) void gemm_xg1(
    const _Float16* __restrict__ A,     // h0 [75][112][128] fp16
    const float* __restrict__ W1,       // wih1 [512][128] f32
    const float* __restrict__ bi1, const float* __restrict__ bh1,
    float* __restrict__ C) {
    constexpr int Ks = 4, LDK = 136, HP = 64, Kv = 128, N = 512;
    __shared__ __align__(16) _Float16 Al[64][LDK];
    __shared__ __align__(16) _Float16 Wl[64][LDK];

    const int tid = threadIdx.x;
    const int tt = blockIdx.x >> 1;
    const int boff = (blockIdx.x & 1) * 48;
    const int n0 = blockIdx.y * 64;

    for (int idx = tid; idx < 64 * HP; idx += 256) {
        int row = idx / HP;
        int k = (idx - row * HP) * 2;
        unsigned int va = *(const unsigned int*)(A + (size_t)(tt * 112 + boff + row) * Kv + k);
        int n = n0 + row;
        int src = (n & 3) * 128 + (n >> 2);
        float f0 = W1[(size_t)src * 128 + k];
        float f1 = W1[(size_t)src * 128 + k + 1];
        _Float16 h2[2] = {(_Float16)f0, (_Float16)f1};
        *(unsigned int*)&Al[row][k] = va;
        *(unsigned int*)&Wl[row][k] = *(unsigned int*)h2;
    }
    __syncthreads();

    const int w = tid >> 6, l = tid & 63, hi = l >> 4;
    half8 a[Ks];
    #pragma unroll
    for (int kk = 0; kk < Ks; ++kk)
        a[kk] = *(const half8*)&Al[w * 16 + (l & 15)][kk * 32 + hi * 8];

    f32x4 acc[4];
    #pragma unroll
    for (int jt = 0; jt < 4; ++jt) {
        acc[jt] = f32x4{0.f, 0.f, 0.f, 0.f};
        #pragma unroll
        for (int kk = 0; kk < Ks; ++kk) {
            half8 b = *(const half8*)&Wl[jt * 16 + (l & 15)][kk * 32 + hi * 8];
            acc[jt] = __builtin_amdgcn_mfma_f32_16x16x32_f16(a[kk], b, acc[jt], 0, 0, 0);
        }
    }

    const int bx = (boff >> 2) + w * 4 + hi;
    #pragma unroll
    for (int jt = 0; jt < 4; ++jt) {
        int n = n0 + jt * 16 + (l & 15);
        int src = (n & 3) * 128 + (n >> 2);
        float bs = bi1[src] + bh1[src];
        f32x4 v = acc[jt];
        v[0] += bs; v[1] += bs; v[2] += bs; v[3] += bs;
        *(f32x4*)(C + ((size_t)(tt * 28 + bx) * N + n) * 4) = v;
    }
}

#define FTAIL                                                                 \
    __builtin_amdgcn_sched_barrier(0);                                        \
    asm volatile("s_waitcnt lgkmcnt(0)");                                     \
    __builtin_amdgcn_sched_barrier(0);                                        \
    __builtin_amdgcn_s_barrier();                                             \
    __builtin_amdgcn_sched_barrier(0);

#define PICK(A4) ((hi & 2) ? ((hi & 1) ? A4[3] : A4[2]) : ((hi & 1) ? A4[1] : A4[0]))

#define ACT(aI, aF, aG4, aO)                                                  \
    float gI = PICK(aI), gF = PICK(aF), gG = PICK(aG4), gO = PICK(aO);        \
    float si = sigmf(gI), sf = sigmf(gF), tg = tanhx(gG), so = sigmf(gO);     \
    float cn = sf * cst + si * tg;                                            \
    cst = cn;                                                                 \
    float hn = so * tanhx(cn);                                                \
    _Float16 hv = (_Float16)hn;

// ---------------------------------------------------------------------------
// Layer-0 recurrence. __launch_bounds__(512, 2): 8 waves = 2/SIMD -> VGPR
// cap 256; grid is 25 blocks (1 block/CU) so occupancy is irrelevant and the
// full ~144-live set (weights + 3-deep P) stays in registers (no remat).
// ---------------------------------------------------------------------------
__global__ __launch_bounds__(512, 2) void lstm_rec0(
    const float* __restrict__ xg,       // [78][28][512][4] f32
    const float* __restrict__ whhf,     // whh0 [512][128] f32
    _Float16* __restrict__ hout) {      // [75][112][128] fp16
    constexpr int H = 128, Ks = 4, LDH = 160;
    constexpr int XSTR = 448 * H;
    constexpr int HSTR = 112 * H;

    __shared__ __align__(16) _Float16 hbuf[2][4][LDH];

    const int tid = threadIdx.x;
    const int w = tid >> 6, l = tid & 63, hi = l >> 4;
    const int col = w * 16 + (l & 15);
    const int blk = blockIdx.x;

    half8 bw[4][Ks];
    #pragma unroll
    for (int G = 0; G < 4; ++G)
        #pragma unroll
        for (int kk = 0; kk < Ks; ++kk)
            bw[G][kk] = cvt8(whhf + (size_t)(G * H + col) * H + kk * 32 + hi * 8);

    for (int i = tid; i < 2 * 4 * LDH; i += 512) ((_Float16*)hbuf)[i] = (_Float16)0;
    __syncthreads();

    const float* xp = xg + (size_t)blk * (4 * H * 4) + col * 16;
    _Float16* hop = hout + (size_t)(blk * 4 + hi) * H + col;

    f32x4 P0[4], P1[4], P2[4];
#define XLOAD(PA)                                                             \
    PA[0] = *(const f32x4*)(xp + 0);                                          \
    PA[1] = *(const f32x4*)(xp + 4);                                          \
    PA[2] = *(const f32x4*)(xp + 8);                                          \
    PA[3] = *(const f32x4*)(xp + 12);                                         \
    xp += XSTR;

    XLOAD(P0)
    XLOAD(P1)
    XLOAD(P2)

    float cst = 0.f;

#define LSTM_STEP(PA, CUR)                                                    \
    {                                                                         \
        half8 afr[Ks];                                                        \
        _Pragma("unroll") for (int kk = 0; kk < Ks; ++kk)                     \
            afr[kk] = *(const half8*)&hbuf[CUR][(l & 15) & 3][kk * 32 + hi * 8]; \
        f32x4 aI = PA[0], aF = PA[1], aG4 = PA[2], aO = PA[3];                \
        XLOAD(PA)                                                             \
        _Pragma("unroll") for (int kk = 0; kk < Ks; ++kk) {                   \
            aI = __builtin_amdgcn_mfma_f32_16x16x32_f16(afr[kk], bw[0][kk], aI, 0, 0, 0);  \
            aF = __builtin_amdgcn_mfma_f32_16x16x32_f16(afr[kk], bw[1][kk], aF, 0, 0, 0);  \
            aG4 = __builtin_amdgcn_mfma_f32_16x16x32_f16(afr[kk], bw[2][kk], aG4, 0, 0, 0);\
            aO = __builtin_amdgcn_mfma_f32_16x16x32_f16(afr[kk], bw[3][kk], aO, 0, 0, 0);  \
        }                                                                     \
        ACT(aI, aF, aG4, aO)                                                  \
        hbuf[CUR ^ 1][hi][col] = hv;                                          \
        *hop = hv;                                                            \
        hop += HSTR;                                                          \
        FTAIL                                                                 \
    }

    #pragma unroll 1
    for (int it = 0; it < 12; ++it) {
        LSTM_STEP(P0, 0) LSTM_STEP(P1, 1) LSTM_STEP(P2, 0)
        LSTM_STEP(P0, 1) LSTM_STEP(P1, 0) LSTM_STEP(P2, 1)
    }
    LSTM_STEP(P0, 0) LSTM_STEP(P1, 1) LSTM_STEP(P2, 0)
#undef LSTM_STEP
#undef XLOAD
}

// ---------------------------------------------------------------------------
// rec1xg: 25 blocks x 768 threads (12 waves). __launch_bounds__(768, 3):
// 12 waves = exactly 3/SIMD -> VGPR cap ~170 >= the A-role's ~140 live
// (round-14 ran this kernel at the heuristic's 68 VGPR and scratch-thrashed
// to 72 us; the cap arithmetic fits this time, unlike pair<128>'s 190>128).
// Waves 0-7 = L1 recurrence (xg1 C-init, publishes h1 into LDS pipe hp);
// waves 8-11 = xg2 = wih2*h1 + b2 at lag 1, written in quad-L2's layout.
// ---------------------------------------------------------------------------
__global__ __launch_bounds__(768, 3) void rec1xg(
    const float* __restrict__ xg1,      // [78][28][512][4] f32
    const float* __restrict__ whh1f,    // whh1 [512][128] f32
    const float* __restrict__ wih2f,    // wih2 [256][128] f32
    const float* __restrict__ bi2, const float* __restrict__ bh2,
    float* __restrict__ xg2) {          // [78][28][256][4] f32
    constexpr int H = 128, Ks = 4, LDH = 160;
    constexpr int XSTR = 448 * H;

    __shared__ __align__(16) _Float16 hb1[2][4][LDH];
    __shared__ __align__(16) _Float16 hp[2][4][LDH];

    const int tid = threadIdx.x;
    const int w = tid >> 6, l = tid & 63, hi = l >> 4;
    const int lr = (l & 15) & 3;
    const int blk = blockIdx.x;

    for (int i = tid; i < 2 * 4 * LDH; i += 768) {
        ((_Float16*)hb1)[i] = (_Float16)0;
        ((_Float16*)hp)[i] = (_Float16)0;
    }
    __syncthreads();

    float cst = 0.f;

    if (w < 8) {  // ----- A: layer-1 recurrence -----
        const int col = w * 16 + (l & 15);
        half8 bw[4][Ks];
        #pragma unroll
        for (int G = 0; G < 4; ++G)
            #pragma unroll
            for (int kk = 0; kk < Ks; ++kk)
                bw[G][kk] = cvt8(whh1f + (size_t)(G * H + col) * H + kk * 32 + hi * 8);

        const float* xp = xg1 + (size_t)blk * (4 * H * 4) + col * 16;
        f32x4 P0[4], P1[4];
#define XLOADA(PA)                                                            \
        PA[0] = *(const f32x4*)(xp + 0);                                      \
        PA[1] = *(const f32x4*)(xp + 4);                                      \
        PA[2] = *(const f32x4*)(xp + 8);                                      \
        PA[3] = *(const f32x4*)(xp + 12);                                     \
        xp += XSTR;
        XLOADA(P0)
        XLOADA(P1)

#define ASTEP(PA, CUR)                                                        \
        {                                                                     \
            half8 afr[Ks];                                                    \
            _Pragma("unroll") for (int kk = 0; kk < Ks; ++kk)                 \
                afr[kk] = *(const half8*)&hb1[CUR][lr][kk * 32 + hi * 8];     \
            f32x4 aI = PA[0], aF = PA[1], aG4 = PA[2], aO = PA[3];            \
            XLOADA(PA)                                                        \
            _Pragma("unroll") for (int kk = 0; kk < Ks; ++kk) {               \
                aI = __builtin_amdgcn_mfma_f32_16x16x32_f16(afr[kk], bw[0][kk], aI, 0, 0, 0);  \
                aF = __builtin_amdgcn_mfma_f32_16x16x32_f16(afr[kk], bw[1][kk], aF, 0, 0, 0);  \
                aG4 = __builtin_amdgcn_mfma_f32_16x16x32_f16(afr[kk], bw[2][kk], aG4, 0, 0, 0);\
                aO = __builtin_amdgcn_mfma_f32_16x16x32_f16(afr[kk], bw[3][kk], aO, 0, 0, 0);  \
            }                                                                 \
            ACT(aI, aF, aG4, aO)                                              \
            hb1[(CUR) ^ 1][hi][col] = hv;                                     \
            hp[(CUR) ^ 1][hi][col] = hv;                                      \
        }

        #pragma unroll 1
        for (int it = 0; it < 38; ++it) {
            ASTEP(P0, 0)                // s = 2it (always < 75)
            FTAIL
            if (2 * it + 1 < 75) { ASTEP(P1, 1) }  // s = 2it+1
            FTAIL
        }
#undef ASTEP
#undef XLOADA
    } else {  // ----- B: xg2 = wih2 * h1 + b2, lag 1 -----
        const int col = (w - 8) * 16 + (l & 15);
        half8 bwI[4][Ks];
        #pragma unroll
        for (int G = 0; G < 4; ++G)
            #pragma unroll
            for (int kk = 0; kk < Ks; ++kk)
                bwI[G][kk] = cvt8(wih2f + (size_t)(G * 64 + col) * 128 + kk * 32 + hi * 8);
        float bb[4];
        #pragma unroll
        for (int G = 0; G < 4; ++G) bb[G] = bi2[G * 64 + col] + bh2[G * 64 + col];
        float* xq = xg2 + (size_t)blk * 1024 + col * 16;

        #pragma unroll 1
        for (int s = 0; s < 76; ++s) {
            const int cur = s & 1;
            if (s >= 1) {
                half8 air[Ks];
                #pragma unroll
                for (int kk = 0; kk < Ks; ++kk)
                    air[kk] = *(const half8*)&hp[cur][lr][kk * 32 + hi * 8];
                f32x4 acc[4];
                #pragma unroll
                for (int G = 0; G < 4; ++G)
                    acc[G] = f32x4{bb[G], bb[G], bb[G], bb[G]};
                #pragma unroll
                for (int G = 0; G < 4; ++G)
                    #pragma unroll
                    for (int kk = 0; kk < Ks; ++kk)
                        acc[G] = __builtin_amdgcn_mfma_f32_16x16x32_f16(air[kk], bwI[G][kk], acc[G], 0, 0, 0);
                if (hi == 0) {
                    #pragma unroll
                    for (int G = 0; G < 4; ++G)
                        *(f32x4*)(xq + (size_t)(s - 1) * 28672 + G * 4) = acc[G];
                }
            }
            FTAIL
        }
    }
}

// ---------------------------------------------------------------------------
// Quad-fused layers 2,3,4,5 + fused final linear (round-12 proven schedule;
// padded strides; weights/biases converted from f32 at init). 25 blocks x
// 832 threads (13 waves); VGPR need ~60 so default bounds are fine.
// ---------------------------------------------------------------------------
struct QuadPtrs {
    const float* xg;       // [78][28][256][4] f32
    const float* whh2;
    const float* whh3;
    const float* wih3;
    const float* whh4;
    const float* wih4;
    const float* whh5;
    const float* wih5;
    const float* bi3; const float* bh3;
    const float* bi4; const float* bh4;
    const float* bi5; const float* bh5;
    const _Float16* lwI;   // [75][4][16][32] fp16
    const float* lb;       // [60]
    float* outF;           // [100][60]
};

__global__ __launch_bounds__(832) void lstm_quad(QuadPtrs q) {
    __shared__ __align__(16) _Float16 hb2[2][4][96], hp2[2][4][96];
    __shared__ __align__(16) _Float16 hb3[2][4][96], hp3[2][4][96];
    __shared__ __align__(16) _Float16 hb4[2][4][80], hp4[2][4][80];
    __shared__ __align__(16) _Float16 hb5[2][4][80];

    const int tid = threadIdx.x;
    const int w = tid >> 6, l = tid & 63, hi = l >> 4;
    const int lr = (l & 15) & 3;
    const int blk = blockIdx.x;

    for (int i = tid; i < 2 * 4 * 96; i += 832) {
        ((_Float16*)hb2)[i] = (_Float16)0; ((_Float16*)hp2)[i] = (_Float16)0;
        ((_Float16*)hb3)[i] = (_Float16)0; ((_Float16*)hp3)[i] = (_Float16)0;
    }
    for (int i = tid; i < 2 * 4 * 80; i += 832) {
        ((_Float16*)hb4)[i] = (_Float16)0; ((_Float16*)hp4)[i] = (_Float16)0;
        ((_Float16*)hb5)[i] = (_Float16)0;
    }
    __syncthreads();

    float cst = 0.f;

    if (w < 4) {  // ----- L2: xg C-init role -----
        const int col = w * 16 + (l & 15);
        half8 bw[4][2];
        #pragma unroll
        for (int G = 0; G < 4; ++G)
            #pragma unroll
            for (int kk = 0; kk < 2; ++kk)
                bw[G][kk] = cvt8(q.whh2 + (size_t)(G * 64 + col) * 64 + kk * 32 + hi * 8);
        const float* xp = q.xg + (size_t)blk * 1024 + col * 16;
        f32x4 P0[4], P1[4], P2[4];
#define XLOADQ(PA)                                                            \
        PA[0] = *(const f32x4*)(xp + 0);                                      \
        PA[1] = *(const f32x4*)(xp + 4);                                      \
        PA[2] = *(const f32x4*)(xp + 8);                                      \
        PA[3] = *(const f32x4*)(xp + 12);                                     \
        xp += 28672;
        XLOADQ(P0)
        XLOADQ(P1)
        XLOADQ(P2)

#define QA(PA, CUR, S)                                                        \
        {                                                                     \
            if ((S) < 75) {                                                   \
                half8 afr[2];                                                 \
                _Pragma("unroll") for (int kk = 0; kk < 2; ++kk)              \
                    afr[kk] = *(const half8*)&hb2[CUR][lr][kk * 32 + hi * 8]; \
                f32x4 aI = PA[0], aF = PA[1], aG4 = PA[2], aO = PA[3];        \
                XLOADQ(PA)                                                    \
                _Pragma("unroll") for (int kk = 0; kk < 2; ++kk) {            \
                    aI = __builtin_amdgcn_mfma_f32_16x16x32_f16(afr[kk], bw[0][kk], aI, 0, 0, 0);  \
                    aF = __builtin_amdgcn_mfma_f32_16x16x32_f16(afr[kk], bw[1][kk], aF, 0, 0, 0);  \
                    aG4 = __builtin_amdgcn_mfma_f32_16x16x32_f16(afr[kk], bw[2][kk], aG4, 0, 0, 0);\
                    aO = __builtin_amdgcn_mfma_f32_16x16x32_f16(afr[kk], bw[3][kk], aO, 0, 0, 0);  \
                }                                                             \
                ACT(aI, aF, aG4, aO)                                          \
                hb2[(CUR) ^ 1][hi][col] = hv;                                 \
                hp2[(CUR) ^ 1][hi][col] = hv;                                 \
            }                                                                 \
            FTAIL                                                             \
        }
        #pragma unroll 1
        for (int it = 0; it < 13; ++it) {
            const int b6 = it * 6;
            QA(P0, 0, b6 + 0) QA(P1, 1, b6 + 1) QA(P2, 0, b6 + 2)
            QA(P0, 1, b6 + 3) QA(P1, 0, b6 + 4) QA(P2, 1, b6 + 5)
        }
#undef QA
#undef XLOADQ
    } else if (w < 8) {  // ----- L3: H=64, HIN=64, lag 1 -----
        const int col = (w - 4) * 16 + (l & 15);
        half8 bwB[4][2], bwI[4][2];
        #pragma unroll
        for (int G = 0; G < 4; ++G)
            #pragma unroll
            for (int kk = 0; kk < 2; ++kk) {
                bwB[G][kk] = cvt8(q.whh3 + (size_t)(G * 64 + col) * 64 + kk * 32 + hi * 8);
                bwI[G][kk] = cvt8(q.wih3 + (size_t)(G * 64 + col) * 64 + kk * 32 + hi * 8);
            }
        const float bI = q.bi3[col] + q.bh3[col];
        const float bF = q.bi3[64 + col] + q.bh3[64 + col];
        const float bG = q.bi3[128 + col] + q.bh3[128 + col];
        const float bO = q.bi3[192 + col] + q.bh3[192 + col];
        #pragma unroll 1
        for (int s = 0; s < 78; ++s) {
            const int cur = s & 1;
            if (s >= 1 && s <= 75) {
                half8 afr[2], air[2];
                #pragma unroll
                for (int kk = 0; kk < 2; ++kk) {
                    afr[kk] = *(const half8*)&hb3[cur][lr][kk * 32 + hi * 8];
                    air[kk] = *(const half8*)&hp2[cur][lr][kk * 32 + hi * 8];
                }
                f32x4 aI = {bI, bI, bI, bI}, aF = {bF, bF, bF, bF};
                f32x4 aG4 = {bG, bG, bG, bG}, aO = {bO, bO, bO, bO};
                #pragma unroll
                for (int kk = 0; kk < 2; ++kk) {
                    aI = __builtin_amdgcn_mfma_f32_16x16x32_f16(afr[kk], bwB[0][kk], aI, 0, 0, 0);
                    aF = __builtin_amdgcn_mfma_f32_16x16x32_f16(afr[kk], bwB[1][kk], aF, 0, 0, 0);
                    aG4 = __builtin_amdgcn_mfma_f32_16x16x32_f16(afr[kk], bwB[2][kk], aG4, 0, 0, 0);
                    aO = __builtin_amdgcn_mfma_f32_16x16x32_f16(afr[kk], bwB[3][kk], aO, 0, 0, 0);
                }
                #pragma unroll
                for (int kk = 0; kk < 2; ++kk) {
                    aI = __builtin_amdgcn_mfma_f32_16x16x32_f16(air[kk], bwI[0][kk], aI, 0, 0, 0);
                    aF = __builtin_amdgcn_mfma_f32_16x16x32_f16(air[kk], bwI[1][kk], aF, 0, 0, 0);
                    aG4 = __builtin_amdgcn_mfma_f32_16x16x32_f16(air[kk], bwI[2][kk], aG4, 0, 0, 0);
                    aO = __builtin_amdgcn_mfma_f32_16x16x32_f16(air[kk], bwI[3][kk], aO, 0, 0, 0);
                }
                ACT(aI, aF, aG4, aO)
                hb3[cur ^ 1][hi][col] = hv;
                hp3[cur ^ 1][hi][col] = hv;
            }
            FTAIL
        }
    } else if (w < 10) {  // ----- L4: H=32, HIN=64, lag 2 -----
        const int col = (w - 8) * 16 + (l & 15);
        half8 bwB[4], bwI[4][2];
        #pragma unroll
        for (int G = 0; G < 4; ++G) {
            bwB[G] = cvt8(q.whh4 + (size_t)(G * 32 + col) * 32 + hi * 8);
            #pragma unroll
            for (int kk = 0; kk < 2; ++kk)
                bwI[G][kk] = cvt8(q.wih4 + (size_t)(G * 32 + col) * 64 + kk * 32 + hi * 8);
        }
        const float bI = q.bi4[col] + q.bh4[col];
        const float bF = q.bi4[32 + col] + q.bh4[32 + col];
        const float bG = q.bi4[64 + col] + q.bh4[64 + col];
        const float bO = q.bi4[96 + col] + q.bh4[96 + col];
        #pragma unroll 1
        for (int s = 0; s < 78; ++s) {
            const int cur = s & 1;
            if (s >= 2 && s <= 76) {
                half8 afr = *(const half8*)&hb4[cur][lr][hi * 8];
                half8 air[2];
                #pragma unroll
                for (int kk = 0; kk < 2; ++kk)
                    air[kk] = *(const half8*)&hp3[cur][lr][kk * 32 + hi * 8];
                f32x4 aI = {bI, bI, bI, bI}, aF = {bF, bF, bF, bF};
                f32x4 aG4 = {bG, bG, bG, bG}, aO = {bO, bO, bO, bO};
                aI = __builtin_amdgcn_mfma_f32_16x16x32_f16(afr, bwB[0], aI, 0, 0, 0);
                aF = __builtin_amdgcn_mfma_f32_16x16x32_f16(afr, bwB[1], aF, 0, 0, 0);
                aG4 = __builtin_amdgcn_mfma_f32_16x16x32_f16(afr, bwB[2], aG4, 0, 0, 0);
                aO = __builtin_amdgcn_mfma_f32_16x16x32_f16(afr, bwB[3], aO, 0, 0, 0);
                #pragma unroll
                for (int kk = 0; kk < 2; ++kk) {
                    aI = __builtin_amdgcn_mfma_f32_16x16x32_f16(air[kk], bwI[0][kk], aI, 0, 0, 0);
                    aF = __builtin_amdgcn_mfma_f32_16x16x32_f16(air[kk], bwI[1][kk], aF, 0, 0, 0);
                    aG4 = __builtin_amdgcn_mfma_f32_16x16x32_f16(air[kk], bwI[2][kk], aG4, 0, 0, 0);
                    aO = __builtin_amdgcn_mfma_f32_16x16x32_f16(air[kk], bwI[3][kk], aO, 0, 0, 0);
                }
                ACT(aI, aF, aG4, aO)
                hb4[cur ^ 1][hi][col] = hv;
                hp4[cur ^ 1][hi][col] = hv;
            }
            FTAIL
        }
    } else if (w < 12) {  // ----- L5: H=32, HIN=32, lag 3; publishes hb5 -----
        const int col = (w - 10) * 16 + (l & 15);
        half8 bwB[4], bwI[4];
        #pragma unroll
        for (int G = 0; G < 4; ++G) {
            bwB[G] = cvt8(q.whh5 + (size_t)(G * 32 + col) * 32 + hi * 8);
            bwI[G] = cvt8(q.wih5 + (size_t)(G * 32 + col) * 32 + hi * 8);
        }
        const float bI = q.bi5[col] + q.bh5[col];
        const float bF = q.bi5[32 + col] + q.bh5[32 + col];
        const float bG = q.bi5[64 + col] + q.bh5[64 + col];
        const float bO = q.bi5[96 + col] + q.bh5[96 + col];
        #pragma unroll 1
        for (int s = 0; s < 78; ++s) {
            const int cur = s & 1;
            if (s >= 3) {
                half8 afr = *(const half8*)&hb5[cur][lr][hi * 8];
                half8 air = *(const half8*)&hp4[cur][lr][hi * 8];
                f32x4 aI = {bI, bI, bI, bI}, aF = {bF, bF, bF, bF};
                f32x4 aG4 = {bG, bG, bG, bG}, aO = {bO, bO, bO, bO};
                aI = __builtin_amdgcn_mfma_f32_16x16x32_f16(afr, bwB[0], aI, 0, 0, 0);
                aF = __builtin_amdgcn_mfma_f32_16x16x32_f16(afr, bwB[1], aF, 0, 0, 0);
                aG4 = __builtin_amdgcn_mfma_f32_16x16x32_f16(afr, bwB[2], aG4, 0, 0, 0);
                aO = __builtin_amdgcn_mfma_f32_16x16x32_f16(afr, bwB[3], aO, 0, 0, 0);
                aI = __builtin_amdgcn_mfma_f32_16x16x32_f16(air, bwI[0], aI, 0, 0, 0);
                aF = __builtin_amdgcn_mfma_f32_16x16x32_f16(air, bwI[1], aF, 0, 0, 0);
                aG4 = __builtin_amdgcn_mfma_f32_16x16x32_f16(air, bwI[2], aG4, 0, 0, 0);
                aO = __builtin_amdgcn_mfma_f32_16x16x32_f16(air, bwI[3], aO, 0, 0, 0);
                ACT(aI, aF, aG4, aO)
                hb5[cur ^ 1][hi][col] = hv;
            }
            FTAIL
        }
    } else {  // ----- LIN: lag 4 -----
        const int ln = l & 15;
        const _Float16* lwp = q.lwI + (size_t)ln * 32 + hi * 8;
        half8 LA[4], LB[4];
        #pragma unroll
        for (int tl = 0; tl < 4; ++tl) {
            LA[tl] = *(const half8*)(lwp + (size_t)(0 * 4 + tl) * 512);
            LB[tl] = *(const half8*)(lwp + (size_t)(1 * 4 + tl) * 512);
        }
        f32x4 acc[4];
        #pragma unroll
        for (int tl = 0; tl < 4; ++tl) acc[tl] = f32x4{0.f, 0.f, 0.f, 0.f};

        #pragma unroll 1
        for (int it = 0; it < 39; ++it) {
            {  // even step s0 = 2*it, t = s0 - 4, reads hb5[0], uses LA
                int t = 2 * it - 4;
                if (t >= 0) {
                    half8 hf = *(const half8*)&hb5[0][lr][hi * 8];
                    #pragma unroll
                    for (int tl = 0; tl < 4; ++tl)
                        acc[tl] = __builtin_amdgcn_mfma_f32_16x16x32_f16(LA[tl], hf, acc[tl], 0, 0, 0);
                }
                int tn = t + 2;
                if (tn < 0) tn = 0;
                if (tn > 74) tn = 74;
                #pragma unroll
                for (int tl = 0; tl < 4; ++tl)
                    LA[tl] = *(const half8*)(lwp + ((size_t)tn * 4 + tl) * 512);
                FTAIL
            }
            {  // odd step s1 = 2*it+1, t = s1 - 4, reads hb5[1], uses LB
                int t = 2 * it - 3;
                if (t >= 0) {
                    half8 hf = *(const half8*)&hb5[1][lr][hi * 8];
                    #pragma unroll
                    for (int tl = 0; tl < 4; ++tl)
                        acc[tl] = __builtin_amdgcn_mfma_f32_16x16x32_f16(LB[tl], hf, acc[tl], 0, 0, 0);
                }
                int tn = t + 2;
                if (tn < 0) tn = 0;
                if (tn > 74) tn = 74;
                #pragma unroll
                for (int tl = 0; tl < 4; ++tl)
                    LB[tl] = *(const half8*)(lwp + ((size_t)tn * 4 + tl) * 512);
                FTAIL
            }
        }
        {  // post-loop: t = 74 (hb5[0] stable after final barrier)
            half8 hf = *(const half8*)&hb5[0][lr][hi * 8];
            #pragma unroll
            for (int tl = 0; tl < 4; ++tl)
                acc[tl] = __builtin_amdgcn_mfma_f32_16x16x32_f16(LA[tl], hf, acc[tl], 0, 0, 0);
        }
        if (ln < 4) {
            int b = blk * 4 + ln;
            #pragma unroll
            for (int tl = 0; tl < 4; ++tl)
                #pragma unroll
                for (int r = 0; r < 4; ++r) {
                    int o = tl * 16 + hi * 4 + r;
                    if (o < 60) q.outF[b * 60 + o] = acc[tl][r] + q.lb[o];
                }
        }
    }
}

// ---------------------------------------------------------------------------
extern "C" void kernel_launch(void* const* d_in, const int* in_sizes, int n_in,
                              void* d_out, int out_size, void* d_ws, size_t ws_size,
                              hipStream_t stream) {
    const float* x = (const float*)d_in[0];
    const float* wih[6];
    const float* whhp[6];
    const float* bih[6];
    const float* bhh[6];
    for (int i = 0; i < 6; ++i) {
        wih[i] = (const float*)d_in[1 + 4 * i];
        whhp[i] = (const float*)d_in[2 + 4 * i];
        bih[i] = (const float*)d_in[3 + 4 * i];
        bhh[i] = (const float*)d_in[4 + 4 * i];
    }
    const float* lw = (const float*)d_in[25];
    const float* lb = (const float*)d_in[26];
    float* out = (float*)d_out;

    char* ws = (char*)d_ws;
    size_t cur = 0;
    auto alloc = [&](size_t b) {
        size_t o = cur;
        cur += (b + 255) & ~(size_t)255;
        return o;
    };
    _Float16* lwI = (_Float16*)(ws + alloc(153600 * 2));
    float* xgA = (float*)(ws + alloc((size_t)78 * 28 * 512 * 4 * 4));   // xg0, then xg1
    float* xgB = (float*)(ws + alloc((size_t)78 * 28 * 256 * 4 * 4));   // xg2
    _Float16* h0 = (_Float16*)(ws + alloc((size_t)75 * 112 * 128 * 2));

    prep_lw<<<600, 256, 0, stream>>>(lw, lwI);

    // layer 0: xg from f32 x + f32 wih0, then recurrence (writes h0)
    gemm_xg0<<<dim3(150, 8), 256, 0, stream>>>(x, wih[0], bih[0], bhh[0], xgA);
    lstm_rec0<<<25, 512, 0, stream>>>(xgA, whhp[0], h0);
    // layer 1: xg from h0 + f32 wih1 (reuses xgA), then rec1 + on-the-fly xg2
    gemm_xg1<<<dim3(150, 8), 256, 0, stream>>>(h0, wih[1], bih[1], bhh[1], xgA);
    rec1xg<<<25, 768, 0, stream>>>(xgA, whhp[1], wih[2], bih[2], bhh[2], xgB);
    // layers 2..5 + final linear, all fused
    QuadPtrs q;
    q.xg = xgB;
    q.whh2 = whhp[2]; q.whh3 = whhp[3]; q.wih3 = wih[3];
    q.whh4 = whhp[4]; q.wih4 = wih[4]; q.whh5 = whhp[5]; q.wih5 = wih[5];
    q.bi3 = bih[3]; q.bh3 = bhh[3];
    q.bi4 = bih[4]; q.bh4 = bhh[4];
    q.bi5 = bih[5]; q.bh5 = bhh[5];
    q.lwI = lwI; q.lb = lb; q.outF = out;
    lstm_quad<<<25, 832, 0, stream>>>(q);
}

// Round 16
// 185.280 us; speedup vs baseline: 1.1445x; 1.1445x over previous
//
#include <hip/hip_runtime.h>

using half8 = __attribute__((ext_vector_type(8))) _Float16;
using f32x4 = __attribute__((ext_vector_type(4))) float;

__device__ __forceinline__ float sigmf(float x) {
    return __builtin_amdgcn_rcpf(1.0f + __expf(-x));
}
__device__ __forceinline__ float tanhx(float x) {
    return 1.0f - 2.0f * __builtin_amdgcn_rcpf(1.0f + __expf(x + x));
}
// load 8 consecutive f32 and convert to half8 (32B-aligned sources)
__device__ __forceinline__ half8 cvt8(const float* p) {
    f32x4 a = *(const f32x4*)p;
    f32x4 b = *(const f32x4*)(p + 4);
    half8 r;
    r[0] = (_Float16)a[0]; r[1] = (_Float16)a[1];
    r[2] = (_Float16)a[2]; r[3] = (_Float16)a[3];
    r[4] = (_Float16)b[0]; r[5] = (_Float16)b[1];
    r[6] = (_Float16)b[2]; r[7] = (_Float16)b[3];
    return r;
}

// ---------------------------------------------------------------------------
// Prep: lwI = lin_w as [75][4][16][32] fp16, plus fp16 copies of whh0/whh1
// (the rec kernels' in-register weights -- preconverted so the rec hot loop
// never touches f32 weights; rounds 7-12 measured this config at 41.2 us).
// ---------------------------------------------------------------------------
__global__ __launch_bounds__(256) void prep_kernel(
    const float* __restrict__ lw, const float* __restrict__ whh0,
    const float* __restrict__ whh1, _Float16* __restrict__ lwI,
    _Float16* __restrict__ wH0, _Float16* __restrict__ wH1) {
    int i = blockIdx.x * 256 + threadIdx.x;
    if (i < 153600) {  // lwI [75][4][16][32]
        int t = i >> 11;
        int rem = i & 2047;
        int tile = rem >> 9, op = (rem >> 5) & 15, hc = rem & 31;
        int o = tile * 16 + op;
        float v = (o < 60) ? lw[(size_t)o * 2400 + t * 32 + hc] : 0.0f;
        lwI[i] = (_Float16)v;
        return;
    }
    i -= 153600;
    if (i < 65536) { wH0[i] = (_Float16)whh0[i]; return; }
    i -= 65536;
    if (i < 65536) { wH1[i] = (_Float16)whh1[i]; return; }
}

// ---------------------------------------------------------------------------
// Layer-0 xg GEMM: reads f32 x AND f32 wih0 directly (converts during LDS
// staging; W rows interleaved on the fly: n -> src (n&3)*128+(n>>2)).
// Output layout [75][28][512][4] f32 (round-7 proven fragment layout).
// ---------------------------------------------------------------------------
__global__ __launch_bounds__(256) void gemm_xg0(
    const float* __restrict__ X,        // [100][75][75] f32
    const float* __restrict__ W0,       // wih0 [512][75] f32
    const float* __restrict__ bi0, const float* __restrict__ bh0,
    float* __restrict__ C) {
    constexpr int Ks = 3, LDK = 104, HP = 48, N = 512;
    __shared__ __align__(16) _Float16 Al[64][LDK];
    __shared__ __align__(16) _Float16 Wl[64][LDK];

    const int tid = threadIdx.x;
    const int tt = blockIdx.x >> 1;
    const int boff = (blockIdx.x & 1) * 48;
    const int n0 = blockIdx.y * 64;

    for (int idx = tid; idx < 64 * HP; idx += 256) {
        int row = idx / HP;
        int k = (idx - row * HP) * 2;
        unsigned int va = 0, vw = 0;
        int b = boff + row;
        if (b < 100 && k < 75) {
            float f0 = X[((size_t)b * 75 + tt) * 75 + k];
            float f1 = (k + 1 < 75) ? X[((size_t)b * 75 + tt) * 75 + k + 1] : 0.0f;
            _Float16 h2[2] = {(_Float16)f0, (_Float16)f1};
            va = *(unsigned int*)h2;
        }
        if (k < 75) {
            int n = n0 + row;
            int src = (n & 3) * 128 + (n >> 2);
            float f0 = W0[(size_t)src * 75 + k];
            float f1 = (k + 1 < 75) ? W0[(size_t)src * 75 + k + 1] : 0.0f;
            _Float16 h2[2] = {(_Float16)f0, (_Float16)f1};
            vw = *(unsigned int*)h2;
        }
        *(unsigned int*)&Al[row][k] = va;
        *(unsigned int*)&Wl[row][k] = vw;
    }
    __syncthreads();

    const int w = tid >> 6, l = tid & 63, hi = l >> 4;
    half8 a[Ks];
    #pragma unroll
    for (int kk = 0; kk < Ks; ++kk)
        a[kk] = *(const half8*)&Al[w * 16 + (l & 15)][kk * 32 + hi * 8];

    f32x4 acc[4];
    #pragma unroll
    for (int jt = 0; jt < 4; ++jt) {
        acc[jt] = f32x4{0.f, 0.f, 0.f, 0.f};
        #pragma unroll
        for (int kk = 0; kk < Ks; ++kk) {
            half8 b = *(const half8*)&Wl[jt * 16 + (l & 15)][kk * 32 + hi * 8];
            acc[jt] = __builtin_amdgcn_mfma_f32_16x16x32_f16(a[kk], b, acc[jt], 0, 0, 0);
        }
    }

    const int bx = (boff >> 2) + w * 4 + hi;
    #pragma unroll
    for (int jt = 0; jt < 4; ++jt) {
        int n = n0 + jt * 16 + (l & 15);
        int src = (n & 3) * 128 + (n >> 2);
        float bs = bi0[src] + bh0[src];
        f32x4 v = acc[jt];
        v[0] += bs; v[1] += bs; v[2] += bs; v[3] += bs;
        *(f32x4*)(C + ((size_t)(tt * 28 + bx) * N + n) * 4) = v;
    }
}

// ---------------------------------------------------------------------------
// xg GEMM for layers 1,2: A = h fp16 [75][112][128], W = f32 [4*HO][128]
// (interleaved on load: n -> src (n&3)*HO+(n>>2)). Output [75][28][4*HO][4].
// ---------------------------------------------------------------------------
template <int HO>
__global__ __launch_bounds__(256) void gemm_xgN(
    const _Float16* __restrict__ A,     // [75][112][128] fp16
    const float* __restrict__ Wf,       // [4*HO][128] f32
    const float* __restrict__ bi, const float* __restrict__ bh,
    float* __restrict__ C) {
    constexpr int Ks = 4, LDK = 136, HP = 64, Kv = 128, N = 4 * HO;
    __shared__ __align__(16) _Float16 Al[64][LDK];
    __shared__ __align__(16) _Float16 Wl[64][LDK];

    const int tid = threadIdx.x;
    const int tt = blockIdx.x >> 1;
    const int boff = (blockIdx.x & 1) * 48;
    const int n0 = blockIdx.y * 64;

    for (int idx = tid; idx < 64 * HP; idx += 256) {
        int row = idx / HP;
        int k = (idx - row * HP) * 2;
        unsigned int va = *(const unsigned int*)(A + (size_t)(tt * 112 + boff + row) * Kv + k);
        int n = n0 + row;
        int src = (n & 3) * HO + (n >> 2);
        float f0 = Wf[(size_t)src * 128 + k];
        float f1 = Wf[(size_t)src * 128 + k + 1];
        _Float16 h2[2] = {(_Float16)f0, (_Float16)f1};
        *(unsigned int*)&Al[row][k] = va;
        *(unsigned int*)&Wl[row][k] = *(unsigned int*)h2;
    }
    __syncthreads();

    const int w = tid >> 6, l = tid & 63, hi = l >> 4;
    half8 a[Ks];
    #pragma unroll
    for (int kk = 0; kk < Ks; ++kk)
        a[kk] = *(const half8*)&Al[w * 16 + (l & 15)][kk * 32 + hi * 8];

    f32x4 acc[4];
    #pragma unroll
    for (int jt = 0; jt < 4; ++jt) {
        acc[jt] = f32x4{0.f, 0.f, 0.f, 0.f};
        #pragma unroll
        for (int kk = 0; kk < Ks; ++kk) {
            half8 b = *(const half8*)&Wl[jt * 16 + (l & 15)][kk * 32 + hi * 8];
            acc[jt] = __builtin_amdgcn_mfma_f32_16x16x32_f16(a[kk], b, acc[jt], 0, 0, 0);
        }
    }

    const int bx = (boff >> 2) + w * 4 + hi;
    #pragma unroll
    for (int jt = 0; jt < 4; ++jt) {
        int n = n0 + jt * 16 + (l & 15);
        int src = (n & 3) * HO + (n >> 2);
        float bs = bi[src] + bh[src];
        f32x4 v = acc[jt];
        v[0] += bs; v[1] += bs; v[2] += bs; v[3] += bs;
        *(f32x4*)(C + ((size_t)(tt * 28 + bx) * N + n) * 4) = v;
    }
}

#define FTAIL                                                                 \
    __builtin_amdgcn_sched_barrier(0);                                        \
    asm volatile("s_waitcnt lgkmcnt(0)");                                     \
    __builtin_amdgcn_sched_barrier(0);                                        \
    __builtin_amdgcn_s_barrier();                                             \
    __builtin_amdgcn_sched_barrier(0);

#define PICK(A4) ((hi & 2) ? ((hi & 1) ? A4[3] : A4[2]) : ((hi & 1) ? A4[1] : A4[0]))

#define ACT(aI, aF, aG4, aO)                                                  \
    float gI = PICK(aI), gF = PICK(aF), gG = PICK(aG4), gO = PICK(aO);        \
    float si = sigmf(gI), sf = sigmf(gF), tg = tanhx(gG), so = sigmf(gO);     \
    float cn = sf * cst + si * tg;                                            \
    cst = cn;                                                                 \
    float hn = so * tanhx(cn);                                                \
    _Float16 hv = (_Float16)hn;

// ---------------------------------------------------------------------------
// Recurrent layer H=128 (round-7..12 PROVEN template, fp16 weights, default
// launch bounds; only change: LDH 136->160 for uniform 2-way bank aliasing).
// ---------------------------------------------------------------------------
__global__ __launch_bounds__(512) void lstm_rec(
    const float* __restrict__ xg,       // [78][28][512][4] f32
    const _Float16* __restrict__ whh,   // [512][128] fp16
    _Float16* __restrict__ hout) {      // [75][112][128] fp16
    constexpr int H = 128, Ks = 4, LDH = 160;
    constexpr int XSTR = 448 * H;
    constexpr int HSTR = 112 * H;

    __shared__ __align__(16) _Float16 hbuf[2][4][LDH];

    const int tid = threadIdx.x;
    const int w = tid >> 6, l = tid & 63, hi = l >> 4;
    const int col = w * 16 + (l & 15);
    const int blk = blockIdx.x;

    half8 bw[4][Ks];
    #pragma unroll
    for (int G = 0; G < 4; ++G)
        #pragma unroll
        for (int kk = 0; kk < Ks; ++kk)
            bw[G][kk] = *(const half8*)(whh + (size_t)(G * H + col) * H + kk * 32 + hi * 8);

    for (int i = tid; i < 2 * 4 * LDH; i += 512) ((_Float16*)hbuf)[i] = (_Float16)0;
    __syncthreads();

    const float* xp = xg + (size_t)blk * (4 * H * 4) + col * 16;
    _Float16* hop = hout + (size_t)(blk * 4 + hi) * H + col;

    f32x4 P0[4], P1[4], P2[4];
#define XLOAD(PA)                                                             \
    PA[0] = *(const f32x4*)(xp + 0);                                          \
    PA[1] = *(const f32x4*)(xp + 4);                                          \
    PA[2] = *(const f32x4*)(xp + 8);                                          \
    PA[3] = *(const f32x4*)(xp + 12);                                         \
    xp += XSTR;

    XLOAD(P0)
    XLOAD(P1)
    XLOAD(P2)

    float cst = 0.f;

#define LSTM_STEP(PA, CUR)                                                    \
    {                                                                         \
        half8 afr[Ks];                                                        \
        _Pragma("unroll") for (int kk = 0; kk < Ks; ++kk)                     \
            afr[kk] = *(const half8*)&hbuf[CUR][(l & 15) & 3][kk * 32 + hi * 8]; \
        f32x4 aI = PA[0], aF = PA[1], aG4 = PA[2], aO = PA[3];                \
        XLOAD(PA)                                                             \
        _Pragma("unroll") for (int kk = 0; kk < Ks; ++kk) {                   \
            aI = __builtin_amdgcn_mfma_f32_16x16x32_f16(afr[kk], bw[0][kk], aI, 0, 0, 0);  \
            aF = __builtin_amdgcn_mfma_f32_16x16x32_f16(afr[kk], bw[1][kk], aF, 0, 0, 0);  \
            aG4 = __builtin_amdgcn_mfma_f32_16x16x32_f16(afr[kk], bw[2][kk], aG4, 0, 0, 0);\
            aO = __builtin_amdgcn_mfma_f32_16x16x32_f16(afr[kk], bw[3][kk], aO, 0, 0, 0);  \
        }                                                                     \
        ACT(aI, aF, aG4, aO)                                                  \
        hbuf[CUR ^ 1][hi][col] = hv;                                          \
        *hop = hv;                                                            \
        hop += HSTR;                                                          \
        FTAIL                                                                 \
    }

    #pragma unroll 1
    for (int it = 0; it < 12; ++it) {
        LSTM_STEP(P0, 0) LSTM_STEP(P1, 1) LSTM_STEP(P2, 0)
        LSTM_STEP(P0, 1) LSTM_STEP(P1, 0) LSTM_STEP(P2, 1)
    }
    LSTM_STEP(P0, 0) LSTM_STEP(P1, 1) LSTM_STEP(P2, 0)
#undef LSTM_STEP
#undef XLOAD
}

// ---------------------------------------------------------------------------
// Quad-fused layers 2,3,4,5 + fused final linear (round-15 version, passed
// at ~46-48 us / VGPR=64). 25 blocks x 832 threads (13 waves).
// ---------------------------------------------------------------------------
struct QuadPtrs {
    const float* xg;       // [78][28][256][4] f32
    const float* whh2;
    const float* whh3;
    const float* wih3;
    const float* whh4;
    const float* wih4;
    const float* whh5;
    const float* wih5;
    const float* bi3; const float* bh3;
    const float* bi4; const float* bh4;
    const float* bi5; const float* bh5;
    const _Float16* lwI;   // [75][4][16][32] fp16
    const float* lb;       // [60]
    float* outF;           // [100][60]
};

__global__ __launch_bounds__(832) void lstm_quad(QuadPtrs q) {
    __shared__ __align__(16) _Float16 hb2[2][4][96], hp2[2][4][96];
    __shared__ __align__(16) _Float16 hb3[2][4][96], hp3[2][4][96];
    __shared__ __align__(16) _Float16 hb4[2][4][80], hp4[2][4][80];
    __shared__ __align__(16) _Float16 hb5[2][4][80];

    const int tid = threadIdx.x;
    const int w = tid >> 6, l = tid & 63, hi = l >> 4;
    const int lr = (l & 15) & 3;
    const int blk = blockIdx.x;

    for (int i = tid; i < 2 * 4 * 96; i += 832) {
        ((_Float16*)hb2)[i] = (_Float16)0; ((_Float16*)hp2)[i] = (_Float16)0;
        ((_Float16*)hb3)[i] = (_Float16)0; ((_Float16*)hp3)[i] = (_Float16)0;
    }
    for (int i = tid; i < 2 * 4 * 80; i += 832) {
        ((_Float16*)hb4)[i] = (_Float16)0; ((_Float16*)hp4)[i] = (_Float16)0;
        ((_Float16*)hb5)[i] = (_Float16)0;
    }
    __syncthreads();

    float cst = 0.f;

    if (w < 4) {  // ----- L2: xg C-init role -----
        const int col = w * 16 + (l & 15);
        half8 bw[4][2];
        #pragma unroll
        for (int G = 0; G < 4; ++G)
            #pragma unroll
            for (int kk = 0; kk < 2; ++kk)
                bw[G][kk] = cvt8(q.whh2 + (size_t)(G * 64 + col) * 64 + kk * 32 + hi * 8);
        const float* xp = q.xg + (size_t)blk * 1024 + col * 16;
        f32x4 P0[4], P1[4], P2[4];
#define XLOADQ(PA)                                                            \
        PA[0] = *(const f32x4*)(xp + 0);                                      \
        PA[1] = *(const f32x4*)(xp + 4);                                      \
        PA[2] = *(const f32x4*)(xp + 8);                                      \
        PA[3] = *(const f32x4*)(xp + 12);                                     \
        xp += 28672;
        XLOADQ(P0)
        XLOADQ(P1)
        XLOADQ(P2)

#define QA(PA, CUR, S)                                                        \
        {                                                                     \
            if ((S) < 75) {                                                   \
                half8 afr[2];                                                 \
                _Pragma("unroll") for (int kk = 0; kk < 2; ++kk)              \
                    afr[kk] = *(const half8*)&hb2[CUR][lr][kk * 32 + hi * 8]; \
                f32x4 aI = PA[0], aF = PA[1], aG4 = PA[2], aO = PA[3];        \
                XLOADQ(PA)                                                    \
                _Pragma("unroll") for (int kk = 0; kk < 2; ++kk) {            \
                    aI = __builtin_amdgcn_mfma_f32_16x16x32_f16(afr[kk], bw[0][kk], aI, 0, 0, 0);  \
                    aF = __builtin_amdgcn_mfma_f32_16x16x32_f16(afr[kk], bw[1][kk], aF, 0, 0, 0);  \
                    aG4 = __builtin_amdgcn_mfma_f32_16x16x32_f16(afr[kk], bw[2][kk], aG4, 0, 0, 0);\
                    aO = __builtin_amdgcn_mfma_f32_16x16x32_f16(afr[kk], bw[3][kk], aO, 0, 0, 0);  \
                }                                                             \
                ACT(aI, aF, aG4, aO)                                          \
                hb2[(CUR) ^ 1][hi][col] = hv;                                 \
                hp2[(CUR) ^ 1][hi][col] = hv;                                 \
            }                                                                 \
            FTAIL                                                             \
        }
        #pragma unroll 1
        for (int it = 0; it < 13; ++it) {
            const int b6 = it * 6;
            QA(P0, 0, b6 + 0) QA(P1, 1, b6 + 1) QA(P2, 0, b6 + 2)
            QA(P0, 1, b6 + 3) QA(P1, 0, b6 + 4) QA(P2, 1, b6 + 5)
        }
#undef QA
#undef XLOADQ
    } else if (w < 8) {  // ----- L3: H=64, HIN=64, lag 1 -----
        const int col = (w - 4) * 16 + (l & 15);
        half8 bwB[4][2], bwI[4][2];
        #pragma unroll
        for (int G = 0; G < 4; ++G)
            #pragma unroll
            for (int kk = 0; kk < 2; ++kk) {
                bwB[G][kk] = cvt8(q.whh3 + (size_t)(G * 64 + col) * 64 + kk * 32 + hi * 8);
                bwI[G][kk] = cvt8(q.wih3 + (size_t)(G * 64 + col) * 64 + kk * 32 + hi * 8);
            }
        const float bI = q.bi3[col] + q.bh3[col];
        const float bF = q.bi3[64 + col] + q.bh3[64 + col];
        const float bG = q.bi3[128 + col] + q.bh3[128 + col];
        const float bO = q.bi3[192 + col] + q.bh3[192 + col];
        #pragma unroll 1
        for (int s = 0; s < 78; ++s) {
            const int cur = s & 1;
            if (s >= 1 && s <= 75) {
                half8 afr[2], air[2];
                #pragma unroll
                for (int kk = 0; kk < 2; ++kk) {
                    afr[kk] = *(const half8*)&hb3[cur][lr][kk * 32 + hi * 8];
                    air[kk] = *(const half8*)&hp2[cur][lr][kk * 32 + hi * 8];
                }
                f32x4 aI = {bI, bI, bI, bI}, aF = {bF, bF, bF, bF};
                f32x4 aG4 = {bG, bG, bG, bG}, aO = {bO, bO, bO, bO};
                #pragma unroll
                for (int kk = 0; kk < 2; ++kk) {
                    aI = __builtin_amdgcn_mfma_f32_16x16x32_f16(afr[kk], bwB[0][kk], aI, 0, 0, 0);
                    aF = __builtin_amdgcn_mfma_f32_16x16x32_f16(afr[kk], bwB[1][kk], aF, 0, 0, 0);
                    aG4 = __builtin_amdgcn_mfma_f32_16x16x32_f16(afr[kk], bwB[2][kk], aG4, 0, 0, 0);
                    aO = __builtin_amdgcn_mfma_f32_16x16x32_f16(afr[kk], bwB[3][kk], aO, 0, 0, 0);
                }
                #pragma unroll
                for (int kk = 0; kk < 2; ++kk) {
                    aI = __builtin_amdgcn_mfma_f32_16x16x32_f16(air[kk], bwI[0][kk], aI, 0, 0, 0);
                    aF = __builtin_amdgcn_mfma_f32_16x16x32_f16(air[kk], bwI[1][kk], aF, 0, 0, 0);
                    aG4 = __builtin_amdgcn_mfma_f32_16x16x32_f16(air[kk], bwI[2][kk], aG4, 0, 0, 0);
                    aO = __builtin_amdgcn_mfma_f32_16x16x32_f16(air[kk], bwI[3][kk], aO, 0, 0, 0);
                }
                ACT(aI, aF, aG4, aO)
                hb3[cur ^ 1][hi][col] = hv;
                hp3[cur ^ 1][hi][col] = hv;
            }
            FTAIL
        }
    } else if (w < 10) {  // ----- L4: H=32, HIN=64, lag 2 -----
        const int col = (w - 8) * 16 + (l & 15);
        half8 bwB[4], bwI[4][2];
        #pragma unroll
        for (int G = 0; G < 4; ++G) {
            bwB[G] = cvt8(q.whh4 + (size_t)(G * 32 + col) * 32 + hi * 8);
            #pragma unroll
            for (int kk = 0; kk < 2; ++kk)
                bwI[G][kk] = cvt8(q.wih4 + (size_t)(G * 32 + col) * 64 + kk * 32 + hi * 8);
        }
        const float bI = q.bi4[col] + q.bh4[col];
        const float bF = q.bi4[32 + col] + q.bh4[32 + col];
        const float bG = q.bi4[64 + col] + q.bh4[64 + col];
        const float bO = q.bi4[96 + col] + q.bh4[96 + col];
        #pragma unroll 1
        for (int s = 0; s < 78; ++s) {
            const int cur = s & 1;
            if (s >= 2 && s <= 76) {
                half8 afr = *(const half8*)&hb4[cur][lr][hi * 8];
                half8 air[2];
                #pragma unroll
                for (int kk = 0; kk < 2; ++kk)
                    air[kk] = *(const half8*)&hp3[cur][lr][kk * 32 + hi * 8];
                f32x4 aI = {bI, bI, bI, bI}, aF = {bF, bF, bF, bF};
                f32x4 aG4 = {bG, bG, bG, bG}, aO = {bO, bO, bO, bO};
                aI = __builtin_amdgcn_mfma_f32_16x16x32_f16(afr, bwB[0], aI, 0, 0, 0);
                aF = __builtin_amdgcn_mfma_f32_16x16x32_f16(afr, bwB[1], aF, 0, 0, 0);
                aG4 = __builtin_amdgcn_mfma_f32_16x16x32_f16(afr, bwB[2], aG4, 0, 0, 0);
                aO = __builtin_amdgcn_mfma_f32_16x16x32_f16(afr, bwB[3], aO, 0, 0, 0);
                #pragma unroll
                for (int kk = 0; kk < 2; ++kk) {
                    aI = __builtin_amdgcn_mfma_f32_16x16x32_f16(air[kk], bwI[0][kk], aI, 0, 0, 0);
                    aF = __builtin_amdgcn_mfma_f32_16x16x32_f16(air[kk], bwI[1][kk], aF, 0, 0, 0);
                    aG4 = __builtin_amdgcn_mfma_f32_16x16x32_f16(air[kk], bwI[2][kk], aG4, 0, 0, 0);
                    aO = __builtin_amdgcn_mfma_f32_16x16x32_f16(air[kk], bwI[3][kk], aO, 0, 0, 0);
                }
                ACT(aI, aF, aG4, aO)
                hb4[cur ^ 1][hi][col] = hv;
                hp4[cur ^ 1][hi][col] = hv;
            }
            FTAIL
        }
    } else if (w < 12) {  // ----- L5: H=32, HIN=32, lag 3; publishes hb5 -----
        const int col = (w - 10) * 16 + (l & 15);
        half8 bwB[4], bwI[4];
        #pragma unroll
        for (int G = 0; G < 4; ++G) {
            bwB[G] = cvt8(q.whh5 + (size_t)(G * 32 + col) * 32 + hi * 8);
            bwI[G] = cvt8(q.wih5 + (size_t)(G * 32 + col) * 32 + hi * 8);
        }
        const float bI = q.bi5[col] + q.bh5[col];
        const float bF = q.bi5[32 + col] + q.bh5[32 + col];
        const float bG = q.bi5[64 + col] + q.bh5[64 + col];
        const float bO = q.bi5[96 + col] + q.bh5[96 + col];
        #pragma unroll 1
        for (int s = 0; s < 78; ++s) {
            const int cur = s & 1;
            if (s >= 3) {
                half8 afr = *(const half8*)&hb5[cur][lr][hi * 8];
                half8 air = *(const half8*)&hp4[cur][lr][hi * 8];
                f32x4 aI = {bI, bI, bI, bI}, aF = {bF, bF, bF, bF};
                f32x4 aG4 = {bG, bG, bG, bG}, aO = {bO, bO, bO, bO};
                aI = __builtin_amdgcn_mfma_f32_16x16x32_f16(afr, bwB[0], aI, 0, 0, 0);
                aF = __builtin_amdgcn_mfma_f32_16x16x32_f16(afr, bwB[1], aF, 0, 0, 0);
                aG4 = __builtin_amdgcn_mfma_f32_16x16x32_f16(afr, bwB[2], aG4, 0, 0, 0);
                aO = __builtin_amdgcn_mfma_f32_16x16x32_f16(afr, bwB[3], aO, 0, 0, 0);
                aI = __builtin_amdgcn_mfma_f32_16x16x32_f16(air, bwI[0], aI, 0, 0, 0);
                aF = __builtin_amdgcn_mfma_f32_16x16x32_f16(air, bwI[1], aF, 0, 0, 0);
                aG4 = __builtin_amdgcn_mfma_f32_16x16x32_f16(air, bwI[2], aG4, 0, 0, 0);
                aO = __builtin_amdgcn_mfma_f32_16x16x32_f16(air, bwI[3], aO, 0, 0, 0);
                ACT(aI, aF, aG4, aO)
                hb5[cur ^ 1][hi][col] = hv;
            }
            FTAIL
        }
    } else {  // ----- LIN: lag 4 -----
        const int ln = l & 15;
        const _Float16* lwp = q.lwI + (size_t)ln * 32 + hi * 8;
        half8 LA[4], LB[4];
        #pragma unroll
        for (int tl = 0; tl < 4; ++tl) {
            LA[tl] = *(const half8*)(lwp + (size_t)(0 * 4 + tl) * 512);
            LB[tl] = *(const half8*)(lwp + (size_t)(1 * 4 + tl) * 512);
        }
        f32x4 acc[4];
        #pragma unroll
        for (int tl = 0; tl < 4; ++tl) acc[tl] = f32x4{0.f, 0.f, 0.f, 0.f};

        #pragma unroll 1
        for (int it = 0; it < 39; ++it) {
            {  // even step s0 = 2*it, t = s0 - 4, reads hb5[0], uses LA
                int t = 2 * it - 4;
                if (t >= 0) {
                    half8 hf = *(const half8*)&hb5[0][lr][hi * 8];
                    #pragma unroll
                    for (int tl = 0; tl < 4; ++tl)
                        acc[tl] = __builtin_amdgcn_mfma_f32_16x16x32_f16(LA[tl], hf, acc[tl], 0, 0, 0);
                }
                int tn = t + 2;
                if (tn < 0) tn = 0;
                if (tn > 74) tn = 74;
                #pragma unroll
                for (int tl = 0; tl < 4; ++tl)
                    LA[tl] = *(const half8*)(lwp + ((size_t)tn * 4 + tl) * 512);
                FTAIL
            }
            {  // odd step s1 = 2*it+1, t = s1 - 4, reads hb5[1], uses LB
                int t = 2 * it - 3;
                if (t >= 0) {
                    half8 hf = *(const half8*)&hb5[1][lr][hi * 8];
                    #pragma unroll
                    for (int tl = 0; tl < 4; ++tl)
                        acc[tl] = __builtin_amdgcn_mfma_f32_16x16x32_f16(LB[tl], hf, acc[tl], 0, 0, 0);
                }
                int tn = t + 2;
                if (tn < 0) tn = 0;
                if (tn > 74) tn = 74;
                #pragma unroll
                for (int tl = 0; tl < 4; ++tl)
                    LB[tl] = *(const half8*)(lwp + ((size_t)tn * 4 + tl) * 512);
                FTAIL
            }
        }
        {  // post-loop: t = 74 (hb5[0] stable after final barrier)
            half8 hf = *(const half8*)&hb5[0][lr][hi * 8];
            #pragma unroll
            for (int tl = 0; tl < 4; ++tl)
                acc[tl] = __builtin_amdgcn_mfma_f32_16x16x32_f16(LA[tl], hf, acc[tl], 0, 0, 0);
        }
        if (ln < 4) {
            int b = blk * 4 + ln;
            #pragma unroll
            for (int tl = 0; tl < 4; ++tl)
                #pragma unroll
                for (int r = 0; r < 4; ++r) {
                    int o = tl * 16 + hi * 4 + r;
                    if (o < 60) q.outF[b * 60 + o] = acc[tl][r] + q.lb[o];
                }
        }
    }
}

// ---------------------------------------------------------------------------
extern "C" void kernel_launch(void* const* d_in, const int* in_sizes, int n_in,
                              void* d_out, int out_size, void* d_ws, size_t ws_size,
                              hipStream_t stream) {
    const float* x = (const float*)d_in[0];
    const float* wih[6];
    const float* whhp[6];
    const float* bih[6];
    const float* bhh[6];
    for (int i = 0; i < 6; ++i) {
        wih[i] = (const float*)d_in[1 + 4 * i];
        whhp[i] = (const float*)d_in[2 + 4 * i];
        bih[i] = (const float*)d_in[3 + 4 * i];
        bhh[i] = (const float*)d_in[4 + 4 * i];
    }
    const float* lw = (const float*)d_in[25];
    const float* lb = (const float*)d_in[26];
    float* out = (float*)d_out;

    char* ws = (char*)d_ws;
    size_t cur = 0;
    auto alloc = [&](size_t b) {
        size_t o = cur;
        cur += (b + 255) & ~(size_t)255;
        return o;
    };
    _Float16* lwI = (_Float16*)(ws + alloc(153600 * 2));
    _Float16* wH0 = (_Float16*)(ws + alloc(65536 * 2));
    _Float16* wH1 = (_Float16*)(ws + alloc(65536 * 2));
    float* xgA = (float*)(ws + alloc((size_t)78 * 28 * 512 * 4 * 4));   // xg0, then xg1
    float* xgB = (float*)(ws + alloc((size_t)78 * 28 * 256 * 4 * 4));   // xg2
    _Float16* h0 = (_Float16*)(ws + alloc((size_t)75 * 112 * 128 * 2));
    _Float16* h1 = (_Float16*)(ws + alloc((size_t)75 * 112 * 128 * 2));

    prep_kernel<<<1112, 256, 0, stream>>>(lw, whhp[0], whhp[1], lwI, wH0, wH1);

    // layer 0: xg from f32 x + f32 wih0, then recurrence (writes h0)
    gemm_xg0<<<dim3(150, 8), 256, 0, stream>>>(x, wih[0], bih[0], bhh[0], xgA);
    lstm_rec<<<25, 512, 0, stream>>>(xgA, wH0, h0);
    // layer 1: xg from h0 + f32 wih1 (reuses xgA), then recurrence (writes h1)
    gemm_xgN<128><<<dim3(150, 8), 256, 0, stream>>>(h0, wih[1], bih[1], bhh[1], xgA);
    lstm_rec<<<25, 512, 0, stream>>>(xgA, wH1, h1);
    // layer 2 xg GEMM (I=128, H=64)
    gemm_xgN<64><<<dim3(150, 4), 256, 0, stream>>>(h1, wih[2], bih[2], bhh[2], xgB);
    // layers 2..5 + final linear, all fused
    QuadPtrs q;
    q.xg = xgB;
    q.whh2 = whhp[2]; q.whh3 = whhp[3]; q.wih3 = wih[3];
    q.whh4 = whhp[4]; q.wih4 = wih[4]; q.whh5 = whhp[5]; q.wih5 = wih[5];
    q.bi3 = bih[3]; q.bh3 = bhh[3];
    q.bi4 = bih[4]; q.bh4 = bhh[4];
    q.bi5 = bih[5]; q.bh5 = bhh[5];
    q.lwI = lwI; q.lb = lb; q.outF = out;
    lstm_quad<<<25, 832, 0, stream>>>(q);
}